// Round 21
// baseline (156.842 us; speedup 1.0000x reference)
//
#include <hip/hip_runtime.h>

// ---------------------------------------------------------------------------
// EquivariantProductBasisBlock (MACE symmetric contraction + gate + linear)
// N=10000, C=128, D=9, S=10.
// R21 = R20 with prep2's pair loop made COMPILE-TIME: template<KA,KB,P>
// dopairs fully unrolled per wave-uniform q (table lookups fold to consts,
// 12 independent dots pipeline). R20's null showed the stall was the serial
// runtime-k iteration chain (.rodata table load -> addr -> LDS -> 30-FMA),
// not the u3 load source. u2/u1 tails unrolled too. Rest identical.
// ---------------------------------------------------------------------------

#define NN 10000
#define CC 128
#define SS 10
#define NPB 1024
#define MAXBLK 20
#define NPAD (MAXBLK*NPB)        // 20480

typedef unsigned short u16;
typedef unsigned int uint;
typedef __attribute__((ext_vector_type(8))) short bf16x8;
typedef __attribute__((ext_vector_type(4))) float f32x4;

#define AFRAG_U16 4608

// ws layout (floats)
#define OFF_AF   0                          // 1280*4608 u16 = 2,949,120 f
#define OFF_F0   2949120                    // CC*NPAD   = 2,621,440
#define OFF_F1   5570560                    // 3*CC*NPAD = 7,864,320
#define OFF_GKF  13434880                   // 327,680 u16 = 163,840 f
#define OFF_LINF 13598720                   // 32,768 u16 = 16,384 f
#define OFF_ORD  13615104                   // NPAD ints
#define OFF_META 13635584                   // 128 ints
#define OFF_XT   13635712                   // NPAD*CC*16 u16 = 20,971,520 f
// total = 34,607,232 floats = 138.4 MB

constexpr int cPA[45] = {
    0,0,0,0,0,0,0,0,0, 1,1,1,1,1,1,1,1, 2,2,2,2,2,2,2,
    3,3,3,3,3,3, 4,4,4,4,4, 5,5,5,5, 6,6,6, 7,7, 8};
constexpr int cPB[45] = {
    0,1,2,3,4,5,6,7,8, 1,2,3,4,5,6,7,8, 2,3,4,5,6,7,8,
    3,4,5,6,7,8, 4,5,6,7,8, 5,6,7,8, 6,7,8, 7,8, 8};

__device__ __forceinline__ u16 bf16rne(float f) {
    unsigned u = __float_as_uint(f);
    u += 0x7fffu + ((u >> 16) & 1u);
    return (u16)(u >> 16);
}
__device__ __forceinline__ float bf2f(u16 h) {
    return __uint_as_float(((unsigned)h) << 16);
}
__device__ __forceinline__ unsigned pk2(float lo, float hi) {
    unsigned r;
    asm("v_cvt_pk_bf16_f32 %0, %1, %2" : "=v"(r) : "v"(lo), "v"(hi));
    return r;
}

// fully-unrolled pair range [KA,KB) with P-length dots; all offsets fold.
template<int KA, int KB, int P>
__device__ __forceinline__ void dopairs(const float* __restrict__ uls,
                                        const float* __restrict__ w,
                                        u16* __restrict__ myrow) {
#pragma unroll
    for (int k = KA; k < KB; ++k) {
        const int a = cPA[k], b = cPB[k];
        float acc = 0.f;
        if (a == b) {
#pragma unroll
            for (int p = 0; p < P; ++p) acc += uls[(a * 9 + b) * P + p] * w[p];
        } else {
#pragma unroll
            for (int p = 0; p < P; ++p)
                acc += (uls[(a * 9 + b) * P + p] + uls[(b * 9 + a) * P + p]) * w[p];
        }
        int h, g, e;
        if (b == 8) {
            if (a == 8)      { h = 2; g = 0; e = 0; }
            else if (a <= 5) { h = 2; g = 0; e = 2 + a; }
            else if (a == 6) { h = 2; g = 2; e = 0; }
            else             { h = 2; g = 3; e = 0; }
        } else if (a < 4)    { h = 0; g = a; e = b; }
        else                 { h = 1; g = a - 4; e = b; }
        myrow[(h * 4 + g) * 8 + e] = bf16rne(acc);
    }
}

// ---------------- plan: hist + segment map + vend (1 block) ----------------
__global__ __launch_bounds__(256) void k_plan(
    const int* __restrict__ sp, int* __restrict__ cursor,
    int* __restrict__ blk_sp, int* __restrict__ vend) {
    __shared__ int cnt[SS];
    int t = threadIdx.x;
    if (t < SS) cnt[t] = 0;
    __syncthreads();
    for (int i = t; i < NN; i += 256) atomicAdd(&cnt[sp[i]], 1);
    __syncthreads();
    if (t == 0) {
        int pos = 0, b = 0;
        for (int s = 0; s < SS; ++s) {
            cursor[s] = pos;
            int nb = (cnt[s] + NPB - 1) / NPB;
            for (int i = 0; i < nb; ++i) {
                blk_sp[b] = s;
                int rem = cnt[s] - i * NPB;
                vend[b] = rem > NPB ? NPB : rem;
                ++b;
            }
            pos += nb * NPB;
        }
        for (; b < MAXBLK; ++b) { blk_sp[b] = -1; vend[b] = 0; }
    }
}

// ---------------- fused setup: scatter | prep2 | prepf (512 thr) ----------------
#define SC_BLK 20
#define P2_BLK 480
__global__ __launch_bounds__(512) void k_setup2(
    const int* __restrict__ sp, int* __restrict__ cursor, int* __restrict__ order,
    const float* __restrict__ u1_0e, const float* __restrict__ u2_0e, const float* __restrict__ u3_0e,
    const float* __restrict__ u1_1o, const float* __restrict__ u2_1o, const float* __restrict__ u3_1o,
    const float* __restrict__ w1_0e, const float* __restrict__ w2_0e, const float* __restrict__ w3_0e,
    const float* __restrict__ w1_1o, const float* __restrict__ w2_1o, const float* __restrict__ w3_1o,
    u16* __restrict__ af,
    const float* __restrict__ gk, const float* __restrict__ lin0,
    const float* __restrict__ lin1, u16* __restrict__ gkf, u16* __restrict__ linf) {
    __shared__ __align__(16) uint rowbuf[128 * 48];   // 24.6 KB
    __shared__ __align__(16) float uls[2430];         // 9.7 KB (u3 slice)
    int bid = blockIdx.x, t = threadIdx.x;

    if (bid < SC_BLK) {
        int n = bid * 512 + t;
        if (n < NN) {
            int p = atomicAdd(&cursor[sp[n]], 1);
            order[p] = n;
        }
        return;
    }
    if (bid < SC_BLK + P2_BLK) {
        int b2 = bid - SC_BLK;
        int row = b2 % 48, s = b2 / 48;
        int c = t & 127, q = t >> 7;            // q wave-uniform
        int sec = row / 12, idx = row % 12;
        u16* myrow = (u16*)&rowbuf[c * 48];
        for (int i = t; i < 128 * 48; i += 512) rowbuf[i] = 0u;
        if (idx < 9) {
            if (sec < 3) {
                const float* src = u3_1o + (size_t)(sec * 9 + idx) * 2430;
                for (int j = t; j < 2430; j += 512) uls[j] = src[j];
            } else {
                const float* src = u3_0e + (size_t)idx * 1863;
                for (int j = t; j < 1863; j += 512) uls[j] = src[j];
            }
        }
        __syncthreads();

        auto emitl = [&](int j, float v) {
            int h, g, e;
            if (j == 8)      { h = 2; g = 0; e = 1; }
            else if (j <= 5) { h = 2; g = 1; e = 2 + j; }
            else if (j == 6) { h = 2; g = 2; e = 1; }
            else             { h = 2; g = 3; e = 1; }
            myrow[(h * 4 + g) * 8 + e] = bf16rne(v);
        };
        if (idx < 9) {
            int i = idx;
            if (sec < 3) {
                float w[30];
#pragma unroll
                for (int p = 0; p < 30; ++p) w[p] = w3_1o[(s * 30 + p) * CC + c];
                if (q == 0)      dopairs<0, 12, 30>(uls, w, myrow);
                else if (q == 1) dopairs<12, 24, 30>(uls, w, myrow);
                else if (q == 2) dopairs<24, 35, 30>(uls, w, myrow);
                else             dopairs<35, 45, 30>(uls, w, myrow);
                if (q == 3) {
                    float w2[4];
#pragma unroll
                    for (int p = 0; p < 4; ++p) w2[p] = w2_1o[(s * 4 + p) * CC + c];
#pragma unroll
                    for (int j = 0; j < 9; ++j) {
                        const float* u = u2_1o + (size_t)(((sec * 9 + i) * 9 + j)) * 4;
                        float acc = u[0] * w2[0] + u[1] * w2[1] + u[2] * w2[2] + u[3] * w2[3];
                        emitl(j, acc);
                    }
                }
            } else {
                float w[23];
#pragma unroll
                for (int p = 0; p < 23; ++p) w[p] = w3_0e[(s * 23 + p) * CC + c];
                if (q == 0)      dopairs<0, 12, 23>(uls, w, myrow);
                else if (q == 1) dopairs<12, 24, 23>(uls, w, myrow);
                else if (q == 2) dopairs<24, 35, 23>(uls, w, myrow);
                else             dopairs<35, 45, 23>(uls, w, myrow);
                if (q == 3) {
                    float w2[4];
#pragma unroll
                    for (int p = 0; p < 4; ++p) w2[p] = w2_0e[(s * 4 + p) * CC + c];
#pragma unroll
                    for (int j = 0; j < 9; ++j) {
                        const float* u = u2_0e + (size_t)((i * 9 + j)) * 4;
                        float acc = u[0] * w2[0] + u[1] * w2[1] + u[2] * w2[2] + u[3] * w2[3];
                        emitl(j, acc);
                    }
                }
            }
        } else if (idx == 9 && q == 0) {
            if (sec < 3) {
                float wv = w1_1o[s * CC + c];
#pragma unroll
                for (int i = 0; i < 9; ++i) emitl(i, u1_1o[sec * 9 + i] * wv);
            } else {
                float wv = w1_0e[s * CC + c];
#pragma unroll
                for (int i = 0; i < 9; ++i) emitl(i, u1_0e[i] * wv);
            }
        }
        __syncthreads();   // fence before typed readback (R10 TBAA lesson)
        int blk = row >> 4, r16 = row & 15;
#pragma unroll 1
        for (int j = t; j < 1536; j += 512) {
            int c2 = j / 12, chunk = j % 12;
            int h = chunk >> 2, g = chunk & 3;
            uint4 v = *(uint4*)&rowbuf[c2 * 48 + chunk * 4];
            u16* dst = af + (size_t)(c2 * SS + s) * AFRAG_U16
                          + (size_t)((blk * 3 + h) * 64 + g * 16 + r16) * 8;
            *(uint4*)dst = v;
        }
        return;
    }
    // ---- prepf: 2 sub-blocks per block ----
    {
        int b = (bid - (SC_BLK + P2_BLK)) * 2 + (t >> 8);   // 0..175
        int tl = t & 255;
        int lane = tl & 63, ck = tl >> 6;
        if (b < 160) {
            int s = b >> 4, kt = b & 15;
            int k = kt * 16 + (lane & 15);
            u16* dst = gkf + (((size_t)b * 4 + ck) * 64 + lane) * 8;
            const float* src = gk + (size_t)s * CC * 256;
#pragma unroll
            for (int e = 0; e < 8; ++e) {
                int c = ck * 32 + ((lane >> 4) & 3) * 8 + e;
                dst[e] = bf16rne(src[c * 256 + k]);
            }
        } else {
            int bb = b - 160;
            int kt = bb & 7;
            int k = kt * 16 + (lane & 15);
            const float* src = (bb >> 3) ? lin1 : lin0;
            u16* dst = linf + (((size_t)bb * 4 + ck) * 64 + lane) * 8;
#pragma unroll
            for (int e = 0; e < 8; ++e) {
                int c = ck * 32 + ((lane >> 4) & 3) * 8 + e;
                dst[e] = bf16rne(src[c * CC + k]);
            }
        }
    }
}

// ---------------- xpose: nf -> xt[c][pos][16] bf16, sorted positions ----------
#define XROW 577   // uint stride per row (576 would be 16-way bank conflict)
__global__ __launch_bounds__(256) void k_xpose(
    const float* __restrict__ nf, const int* __restrict__ order,
    const int* __restrict__ blk_sp, const int* __restrict__ vend,
    u16* __restrict__ xt) {
    __shared__ uint rows[16 * XROW];   // 36.9 KB
    __shared__ int ords[16];
    int pos0 = blockIdx.x * 16;
    int seg = pos0 / NPB;
    int s = blk_sp[seg];
    int lim = seg * NPB + ((s >= 0) ? vend[seg] : 0);
    int t = threadIdx.x;

    if (t < 16) ords[t] = (pos0 + t < lim) ? order[pos0 + t] : -1;
    __syncthreads();

#pragma unroll 1
    for (int i = t; i < 4608; i += 256) {
        int r = i / 288, j = i % 288;
        int n = ords[r];
        uint2 pk = {0u, 0u};
        if (n >= 0) {
            float4 v = *(const float4*)(nf + (size_t)n * 1152 + j * 4);
            pk.x = pk2(v.x, v.y);
            pk.y = pk2(v.z, v.w);
        }
        *(uint2*)&rows[r * XROW + j * 2] = pk;
    }
    __syncthreads();

    auto elem = [&](int r, int e) -> uint {
        uint w = rows[r * XROW + (e >> 1)];
        return (e & 1) ? (w >> 16) : (w & 0xffffu);
    };
#pragma unroll 1
    for (int i = t; i < 2048; i += 256) {
        int c = i >> 4, r = i & 15;
        uint x0 = elem(r, c);
        uint x1 = elem(r, 128 + c * 3), x2 = elem(r, 128 + c * 3 + 1), x3 = elem(r, 128 + c * 3 + 2);
        uint x4 = elem(r, 512 + c * 5), x5 = elem(r, 512 + c * 5 + 1);
        uint x6 = elem(r, 512 + c * 5 + 2), x7 = elem(r, 512 + c * 5 + 3), x8 = elem(r, 512 + c * 5 + 4);
        uint4 lo = {x0 | (x1 << 16), x2 | (x3 << 16), x4 | (x5 << 16), x6 | (x7 << 16)};
        u16* dst = xt + ((size_t)c * NPAD + pos0 + r) * 16;
        *(uint4*)dst = lo;
        *(uint*)(dst + 8) = x8;
    }
}

// ---------------- symmetric contraction via MFMA (coalesced xt reads) ----------
__global__ __launch_bounds__(128) void k_contract(
    const u16* __restrict__ xt, const int* __restrict__ blk_sp,
    const u16* __restrict__ af_g,
    float* __restrict__ f0t, float* __restrict__ f1t) {
    int bid = blockIdx.x;                 // 0..5119
    int xcd = bid & 7;
    int r = bid >> 3;
    int c = xcd * 16 + (r / 40);
    int t2 = r % 40;
    int seg = t2 >> 1, half = t2 & 1;
    int s = blk_sp[seg];
    if (s < 0) return;

    int tid = threadIdx.x;
    int lane = tid & 63;
    int wq = half * 2 + (tid >> 6);
    int n16 = lane & 15, gg = lane >> 4;

    const bf16x8* ab = (const bf16x8*)(af_g + (size_t)(c * SS + s) * AFRAG_U16);
    bf16x8 a00 = ab[0 * 64 + lane], a01 = ab[1 * 64 + lane], a02 = ab[2 * 64 + lane];
    bf16x8 a10 = ab[3 * 64 + lane], a11 = ab[4 * 64 + lane], a12 = ab[5 * 64 + lane];
    bf16x8 a20 = ab[6 * 64 + lane], a21 = ab[7 * 64 + lane], a22 = ab[8 * 64 + lane];

    int posw = seg * NPB + wq * 16 + n16;
    const u16* xp = xt + (size_t)c * NPAD * 16;

    uint4 qa = *(const uint4*)&xp[(size_t)posw * 16];
    uint  ha = *(const uint*)&xp[(size_t)posw * 16 + 8];
    uint4 qb = *(const uint4*)&xp[(size_t)(posw + 64) * 16];
    uint  hb = *(const uint*)&xp[(size_t)(posw + 64) * 16 + 8];

#pragma unroll 1
    for (int sub = 0; sub < 16; ++sub) {
        uint4 qf = {0u, 0u, 0u, 0u}; uint hf = 0u;
        if (sub < 14) {
            qf = *(const uint4*)&xp[(size_t)(posw + (sub + 2) * 64) * 16];
            hf = *(const uint*)&xp[(size_t)(posw + (sub + 2) * 64) * 16 + 8];
        }

        float xc0 = __uint_as_float(qa.x << 16), xc1 = __uint_as_float(qa.x & 0xffff0000u);
        float xc2 = __uint_as_float(qa.y << 16), xc3 = __uint_as_float(qa.y & 0xffff0000u);
        float xc4 = __uint_as_float(qa.z << 16), xc5 = __uint_as_float(qa.z & 0xffff0000u);
        float xc6 = __uint_as_float(qa.w << 16), xc7 = __uint_as_float(qa.w & 0xffff0000u);
        float xc8 = __uint_as_float(ha << 16);

        float xa0 = (gg == 0) ? xc0 : (gg == 1) ? xc1 : (gg == 2) ? xc2 : xc3;
        float xa1 = (gg == 0) ? xc4 : (gg == 1) ? xc5 : (gg == 2) ? xc6 : xc7;
        float xa2 = (gg == 0) ? xc8 : (gg == 1) ? 1.0f : (gg == 2) ? xc6 : xc7;
        uint4 q0, q1, q2;
        q0.x = pk2(xa0 * xc0, xa0 * xc1);
        q0.y = pk2(xa0 * xc2, xa0 * xc3);
        q0.z = pk2(xa0 * xc4, xa0 * xc5);
        q0.w = pk2(xa0 * xc6, xa0 * xc7);
        q1.x = pk2(xa1 * xc0, xa1 * xc1);
        q1.y = pk2(xa1 * xc2, xa1 * xc3);
        q1.z = pk2(xa1 * xc4, xa1 * xc5);
        q1.w = pk2(xa1 * xc6, xa1 * xc7);
        q2.x = pk2(xa2 * xc8, xa2);
        q2.y = pk2(xa2 * xc0, xa2 * xc1);
        q2.z = pk2(xa2 * xc2, xa2 * xc3);
        q2.w = pk2(xa2 * xc4, xa2 * xc5);
        bf16x8 y0 = __builtin_bit_cast(bf16x8, q0);
        bf16x8 y1 = __builtin_bit_cast(bf16x8, q1);
        bf16x8 y2 = __builtin_bit_cast(bf16x8, q2);

        f32x4 acc0 = {0.f, 0.f, 0.f, 0.f}, acc1 = acc0, acc2 = acc0;
        acc0 = __builtin_amdgcn_mfma_f32_16x16x32_bf16(a00, y0, acc0, 0, 0, 0);
        acc0 = __builtin_amdgcn_mfma_f32_16x16x32_bf16(a01, y1, acc0, 0, 0, 0);
        acc0 = __builtin_amdgcn_mfma_f32_16x16x32_bf16(a02, y2, acc0, 0, 0, 0);
        acc1 = __builtin_amdgcn_mfma_f32_16x16x32_bf16(a10, y0, acc1, 0, 0, 0);
        acc1 = __builtin_amdgcn_mfma_f32_16x16x32_bf16(a11, y1, acc1, 0, 0, 0);
        acc1 = __builtin_amdgcn_mfma_f32_16x16x32_bf16(a12, y2, acc1, 0, 0, 0);
        acc2 = __builtin_amdgcn_mfma_f32_16x16x32_bf16(a20, y0, acc2, 0, 0, 0);
        acc2 = __builtin_amdgcn_mfma_f32_16x16x32_bf16(a21, y1, acc2, 0, 0, 0);
        acc2 = __builtin_amdgcn_mfma_f32_16x16x32_bf16(a22, y2, acc2, 0, 0, 0);

        f32x4 eA = (gg == 0) ? acc0 : (gg == 1) ? acc2 : (gg == 2) ? acc1 : acc0;
        f32x4 eB = (gg == 0) ? acc1 : (gg == 1) ? acc0 : (gg == 2) ? acc2 : acc1;
        f32x4 eC = (gg == 0) ? acc2 : (gg == 1) ? acc1 : (gg == 2) ? acc0 : acc2;
        float dA = eA[0] * xc0 + eA[1] * xc1 + eA[2] * xc2 + eA[3] * xc3;
        float dB = eB[0] * xc4 + eB[1] * xc5 + eB[2] * xc6 + eB[3] * xc7;
        float dC = eC[0] * xc8 + eC[1];
        float p0 = (gg == 0) ? dA : (gg == 1) ? dB : (gg == 2) ? dC : 0.f;
        float p1 = (gg == 0) ? dB : (gg == 1) ? dC : (gg == 2) ? 0.f : dA;
        float p2 = (gg == 0) ? dC : (gg == 1) ? 0.f : (gg == 2) ? dA : dB;
        float p3 = (gg == 0) ? 0.f : (gg == 1) ? dA : (gg == 2) ? dB : dC;
        p0 += __shfl_xor(p0, 16); p1 += __shfl_xor(p1, 16);
        p2 += __shfl_xor(p2, 16); p3 += __shfl_xor(p3, 16);
        p0 += __shfl_xor(p0, 32); p1 += __shfl_xor(p1, 32);
        p2 += __shfl_xor(p2, 32); p3 += __shfl_xor(p3, 32);
        float val = (gg == 0) ? p0 : (gg == 1) ? p1 : (gg == 2) ? p2 : p3;

        int pos = posw + sub * 64;
        if (gg == 3) f0t[(size_t)c * NPAD + pos] = val;
        else         f1t[(size_t)(c * 3 + gg) * NPAD + pos] = val;

        qa = qb; ha = hb; qb = qf; hb = hf;
    }
}

// ---------------- fused gate + equivariant linear (MFMA), 2-way split ----------
#define GSTR 264
__global__ __launch_bounds__(256) void k_post(
    const float* __restrict__ f0t, const float* __restrict__ f1t,
    const u16* __restrict__ gkf, const u16* __restrict__ linf,
    const float* __restrict__ gb, const int* __restrict__ order,
    const int* __restrict__ blk_sp, const int* __restrict__ vend,
    float* __restrict__ out) {
    int tile = blockIdx.x;
    int half = blockIdx.y;
    int s = blk_sp[tile >> 4];
    if (s < 0) return;
    int p0 = tile * 64;
    int vv = vend[tile >> 4];
    int boff = (tile & 15) * 64;

    __shared__ __align__(16) u16 frag[4][4][64][8];
    __shared__ __align__(16) u16 gate_l[64 * GSTR];
    __shared__ int ord[64];

    int t = threadIdx.x, lane = t & 63, w = t >> 6;
    int l15 = lane & 15, lg = lane >> 4;
    if (t < 64) ord[t] = (boff + t < vv) ? order[p0 + t] : -1;

#pragma unroll 1
    for (int it = 0; it < 32; ++it) {
        int posn = t & 63;
        int c = (t >> 6) + 4 * it;
        float v = f0t[(size_t)c * NPAD + p0 + posn];
        frag[posn >> 4][c >> 5][((c >> 3) & 3) * 16 + (posn & 15)][c & 7] = bf16rne(v);
    }
    __syncthreads();

#pragma unroll 1
    for (int kt = 0; kt < 16; ++kt) {
        float bias = gb[s * 256 + kt * 16 + l15];
        f32x4 acc = {bias, bias, bias, bias};
#pragma unroll
        for (int ck = 0; ck < 4; ++ck) {
            bf16x8 a = *(const bf16x8*)&frag[w][ck][lane][0];
            bf16x8 b = *(const bf16x8*)&gkf[(((size_t)(s * 16 + kt)) * 4 + ck) * 512 + lane * 8];
            acc = __builtin_amdgcn_mfma_f32_16x16x32_bf16(a, b, acc, 0, 0, 0);
        }
#pragma unroll
        for (int r = 0; r < 4; ++r) {
            int posn = w * 16 + lg * 4 + r;
            gate_l[posn * GSTR + kt * 16 + l15] = bf16rne(acc[r]);
        }
    }
    __syncthreads();

    const float INV = 0.08838834764831845f;   // 1/sqrt(128)

#pragma unroll 1
    for (int p = 2 * half; p < 2 * half + 2; ++p) {
#pragma unroll 1
        for (int it = 0; it < 4; ++it) {
            int rr = it * 256 + t;
            int pt = rr >> 8, ck = (rr >> 6) & 3, l2 = rr & 63;
            int posn = pt * 16 + (l2 & 15);
            int cb = ck * 32 + (l2 >> 4) * 8;
            u16 res[8];
            if (p == 0) {
                bf16x8 a1 = *(const bf16x8*)&frag[pt][ck][l2][0];
                const u16* gp = &gate_l[posn * GSTR + cb];
#pragma unroll
                for (int e = 0; e < 8; ++e)
                    res[e] = bf16rne(bf2f((u16)a1[e]) * bf2f(gp[e]));
            } else {
                int z = p - 1;
                const u16* gp = &gate_l[posn * GSTR + 128 + cb];
#pragma unroll
                for (int e = 0; e < 8; ++e) {
                    float fv = f1t[((size_t)(cb + e) * 3 + z) * NPAD + p0 + posn];
                    res[e] = bf16rne(fv * bf2f(gp[e]));
                }
            }
            uint4 uv;
            uv.x = (unsigned)res[0] | ((unsigned)res[1] << 16);
            uv.y = (unsigned)res[2] | ((unsigned)res[3] << 16);
            uv.z = (unsigned)res[4] | ((unsigned)res[5] << 16);
            uv.w = (unsigned)res[6] | ((unsigned)res[7] << 16);
            *(uint4*)&frag[pt][ck][l2][0] = uv;
        }
        __syncthreads();

        int lbase = (p == 0) ? 0 : 8;
#pragma unroll 1
        for (int kt = 0; kt < 8; ++kt) {
            f32x4 acc = {0.f, 0.f, 0.f, 0.f};
#pragma unroll
            for (int ck = 0; ck < 4; ++ck) {
                bf16x8 a = *(const bf16x8*)&frag[w][ck][lane][0];
                bf16x8 b = *(const bf16x8*)&linf[(((size_t)(lbase + kt)) * 4 + ck) * 512 + lane * 8];
                acc = __builtin_amdgcn_mfma_f32_16x16x32_bf16(a, b, acc, 0, 0, 0);
            }
            int k = kt * 16 + l15;
            int kk = (p == 0) ? k : (128 + k * 3 + (p - 1));
#pragma unroll
            for (int r = 0; r < 4; ++r) {
                int posn = w * 16 + lg * 4 + r;
                int n = ord[posn];
                if (n >= 0) out[(size_t)n * 512 + kk] = acc[r] * INV;
            }
        }
        __syncthreads();
    }
}

// ---------------------------------------------------------------------------
extern "C" void kernel_launch(void* const* d_in, const int* in_sizes, int n_in,
                              void* d_out, int out_size, void* d_ws, size_t ws_size,
                              hipStream_t stream) {
    const float* nf    = (const float*)d_in[0];
    const int*   sp    = (const int*)  d_in[1];
    const float* u1_0e = (const float*)d_in[2];
    const float* u2_0e = (const float*)d_in[3];
    const float* u3_0e = (const float*)d_in[4];
    const float* u1_1o = (const float*)d_in[5];
    const float* u2_1o = (const float*)d_in[6];
    const float* u3_1o = (const float*)d_in[7];
    const float* w1_0e = (const float*)d_in[8];
    const float* w2_0e = (const float*)d_in[9];
    const float* w3_0e = (const float*)d_in[10];
    const float* w1_1o = (const float*)d_in[11];
    const float* w2_1o = (const float*)d_in[12];
    const float* w3_1o = (const float*)d_in[13];
    const float* gk    = (const float*)d_in[14];
    const float* gb    = (const float*)d_in[15];
    const float* lin0  = (const float*)d_in[16];
    const float* lin1  = (const float*)d_in[17];

    float* ws   = (float*)d_ws;
    u16*  af    = (u16*)(ws + OFF_AF);
    float* f0t  = ws + OFF_F0;
    float* f1t  = ws + OFF_F1;
    u16*  gkf   = (u16*)(ws + OFF_GKF);
    u16*  linf  = (u16*)(ws + OFF_LINF);
    int* order  = (int*)(ws + OFF_ORD);
    int* meta   = (int*)(ws + OFF_META);
    u16*  xt    = (u16*)(ws + OFF_XT);
    int* cursor = meta + 16;
    int* blk_sp = meta + 32;
    int* vend   = meta + 64;

    k_plan<<<1, 256, 0, stream>>>(sp, cursor, blk_sp, vend);
    k_setup2<<<SC_BLK + P2_BLK + 88, 512, 0, stream>>>(
        sp, cursor, order,
        u1_0e, u2_0e, u3_0e, u1_1o, u2_1o, u3_1o,
        w1_0e, w2_0e, w3_0e, w1_1o, w2_1o, w3_1o, af,
        gk, lin0, lin1, gkf, linf);
    k_xpose<<<NPAD / 16, 256, 0, stream>>>(nf, order, blk_sp, vend, xt);
    k_contract<<<5120, 128, 0, stream>>>(xt, blk_sp, af, f0t, f1t);
    dim3 gpost(NPAD / 64, 2);
    k_post<<<gpost, 256, 0, stream>>>(f0t, f1t, gkf, linf, gb, order, blk_sp, vend,
                                      (float*)d_out);
}

// Round 22
// 133.428 us; speedup vs baseline: 1.1755x; 1.1755x over previous
//
#include <hip/hip_runtime.h>

// ---------------------------------------------------------------------------
// EquivariantProductBasisBlock (MACE symmetric contraction + gate + linear)
// N=10000, C=128, D=9, S=10.
// R22 = R21 with the scatter's contended global atomics fixed (Guideline 12):
// per-block LDS histogram + local ranks, ONE global atomicAdd per
// (block,species) -> 200 global atomics instead of 10,000 same-address ops.
// Diagnosis: setup2 pinned at 51us across 3 prep2 rewrites with VALUBusy
// FALLING -> critical path was the untouched atomic scatter (~35ns/op
// contended fetch-add x ~1100 max-species) .
// ---------------------------------------------------------------------------

#define NN 10000
#define CC 128
#define SS 10
#define NPB 1024
#define MAXBLK 20
#define NPAD (MAXBLK*NPB)        // 20480

typedef unsigned short u16;
typedef unsigned int uint;
typedef __attribute__((ext_vector_type(8))) short bf16x8;
typedef __attribute__((ext_vector_type(4))) float f32x4;

#define AFRAG_U16 4608

// ws layout (floats)
#define OFF_AF   0                          // 1280*4608 u16 = 2,949,120 f
#define OFF_F0   2949120                    // CC*NPAD   = 2,621,440
#define OFF_F1   5570560                    // 3*CC*NPAD = 7,864,320
#define OFF_GKF  13434880                   // 327,680 u16 = 163,840 f
#define OFF_LINF 13598720                   // 32,768 u16 = 16,384 f
#define OFF_ORD  13615104                   // NPAD ints
#define OFF_META 13635584                   // 128 ints
#define OFF_XT   13635712                   // NPAD*CC*16 u16 = 20,971,520 f
// total = 34,607,232 floats = 138.4 MB

constexpr int cPA[45] = {
    0,0,0,0,0,0,0,0,0, 1,1,1,1,1,1,1,1, 2,2,2,2,2,2,2,
    3,3,3,3,3,3, 4,4,4,4,4, 5,5,5,5, 6,6,6, 7,7, 8};
constexpr int cPB[45] = {
    0,1,2,3,4,5,6,7,8, 1,2,3,4,5,6,7,8, 2,3,4,5,6,7,8,
    3,4,5,6,7,8, 4,5,6,7,8, 5,6,7,8, 6,7,8, 7,8, 8};

__device__ __forceinline__ u16 bf16rne(float f) {
    unsigned u = __float_as_uint(f);
    u += 0x7fffu + ((u >> 16) & 1u);
    return (u16)(u >> 16);
}
__device__ __forceinline__ float bf2f(u16 h) {
    return __uint_as_float(((unsigned)h) << 16);
}
__device__ __forceinline__ unsigned pk2(float lo, float hi) {
    unsigned r;
    asm("v_cvt_pk_bf16_f32 %0, %1, %2" : "=v"(r) : "v"(lo), "v"(hi));
    return r;
}

// fully-unrolled pair range [KA,KB) with P-length dots; all offsets fold.
template<int KA, int KB, int P>
__device__ __forceinline__ void dopairs(const float* __restrict__ uls,
                                        const float* __restrict__ w,
                                        u16* __restrict__ myrow) {
#pragma unroll
    for (int k = KA; k < KB; ++k) {
        const int a = cPA[k], b = cPB[k];
        float acc = 0.f;
        if (a == b) {
#pragma unroll
            for (int p = 0; p < P; ++p) acc += uls[(a * 9 + b) * P + p] * w[p];
        } else {
#pragma unroll
            for (int p = 0; p < P; ++p)
                acc += (uls[(a * 9 + b) * P + p] + uls[(b * 9 + a) * P + p]) * w[p];
        }
        int h, g, e;
        if (b == 8) {
            if (a == 8)      { h = 2; g = 0; e = 0; }
            else if (a <= 5) { h = 2; g = 0; e = 2 + a; }
            else if (a == 6) { h = 2; g = 2; e = 0; }
            else             { h = 2; g = 3; e = 0; }
        } else if (a < 4)    { h = 0; g = a; e = b; }
        else                 { h = 1; g = a - 4; e = b; }
        myrow[(h * 4 + g) * 8 + e] = bf16rne(acc);
    }
}

// ---------------- plan: hist + segment map + vend (1 block) ----------------
__global__ __launch_bounds__(256) void k_plan(
    const int* __restrict__ sp, int* __restrict__ cursor,
    int* __restrict__ blk_sp, int* __restrict__ vend) {
    __shared__ int cnt[SS];
    int t = threadIdx.x;
    if (t < SS) cnt[t] = 0;
    __syncthreads();
    for (int i = t; i < NN; i += 256) atomicAdd(&cnt[sp[i]], 1);
    __syncthreads();
    if (t == 0) {
        int pos = 0, b = 0;
        for (int s = 0; s < SS; ++s) {
            cursor[s] = pos;
            int nb = (cnt[s] + NPB - 1) / NPB;
            for (int i = 0; i < nb; ++i) {
                blk_sp[b] = s;
                int rem = cnt[s] - i * NPB;
                vend[b] = rem > NPB ? NPB : rem;
                ++b;
            }
            pos += nb * NPB;
        }
        for (; b < MAXBLK; ++b) { blk_sp[b] = -1; vend[b] = 0; }
    }
}

// ---------------- fused setup: scatter | prep2 | prepf (512 thr) ----------------
#define SC_BLK 20
#define P2_BLK 480
__global__ __launch_bounds__(512) void k_setup2(
    const int* __restrict__ sp, int* __restrict__ cursor, int* __restrict__ order,
    const float* __restrict__ u1_0e, const float* __restrict__ u2_0e, const float* __restrict__ u3_0e,
    const float* __restrict__ u1_1o, const float* __restrict__ u2_1o, const float* __restrict__ u3_1o,
    const float* __restrict__ w1_0e, const float* __restrict__ w2_0e, const float* __restrict__ w3_0e,
    const float* __restrict__ w1_1o, const float* __restrict__ w2_1o, const float* __restrict__ w3_1o,
    u16* __restrict__ af,
    const float* __restrict__ gk, const float* __restrict__ lin0,
    const float* __restrict__ lin1, u16* __restrict__ gkf, u16* __restrict__ linf) {
    __shared__ __align__(16) uint rowbuf[128 * 48];   // 24.6 KB
    __shared__ __align__(16) float uls[2430];         // 9.7 KB (u3 slice)
    __shared__ int lcnt[SS];
    __shared__ int gbase[SS];
    int bid = blockIdx.x, t = threadIdx.x;

    if (bid < SC_BLK) {
        // ---- scatter with per-block pre-aggregation (Guideline 12) ----
        if (t < SS) lcnt[t] = 0;
        __syncthreads();
        int n = bid * 512 + t;
        int mys = -1, myrank = 0;
        if (n < NN) {
            mys = sp[n];
            myrank = atomicAdd(&lcnt[mys], 1);     // LDS atomic (fast)
        }
        __syncthreads();
        if (t < SS && lcnt[t] > 0) gbase[t] = atomicAdd(&cursor[t], lcnt[t]);
        __syncthreads();
        if (n < NN) order[gbase[mys] + myrank] = n;
        return;
    }
    if (bid < SC_BLK + P2_BLK) {
        int b2 = bid - SC_BLK;
        int row = b2 % 48, s = b2 / 48;
        int c = t & 127, q = t >> 7;            // q wave-uniform
        int sec = row / 12, idx = row % 12;
        u16* myrow = (u16*)&rowbuf[c * 48];
        for (int i = t; i < 128 * 48; i += 512) rowbuf[i] = 0u;
        if (idx < 9) {
            if (sec < 3) {
                const float* src = u3_1o + (size_t)(sec * 9 + idx) * 2430;
                for (int j = t; j < 2430; j += 512) uls[j] = src[j];
            } else {
                const float* src = u3_0e + (size_t)idx * 1863;
                for (int j = t; j < 1863; j += 512) uls[j] = src[j];
            }
        }
        __syncthreads();

        auto emitl = [&](int j, float v) {
            int h, g, e;
            if (j == 8)      { h = 2; g = 0; e = 1; }
            else if (j <= 5) { h = 2; g = 1; e = 2 + j; }
            else if (j == 6) { h = 2; g = 2; e = 1; }
            else             { h = 2; g = 3; e = 1; }
            myrow[(h * 4 + g) * 8 + e] = bf16rne(v);
        };
        if (idx < 9) {
            int i = idx;
            if (sec < 3) {
                float w[30];
#pragma unroll
                for (int p = 0; p < 30; ++p) w[p] = w3_1o[(s * 30 + p) * CC + c];
                if (q == 0)      dopairs<0, 12, 30>(uls, w, myrow);
                else if (q == 1) dopairs<12, 24, 30>(uls, w, myrow);
                else if (q == 2) dopairs<24, 35, 30>(uls, w, myrow);
                else             dopairs<35, 45, 30>(uls, w, myrow);
                if (q == 3) {
                    float w2[4];
#pragma unroll
                    for (int p = 0; p < 4; ++p) w2[p] = w2_1o[(s * 4 + p) * CC + c];
#pragma unroll
                    for (int j = 0; j < 9; ++j) {
                        const float* u = u2_1o + (size_t)(((sec * 9 + i) * 9 + j)) * 4;
                        float acc = u[0] * w2[0] + u[1] * w2[1] + u[2] * w2[2] + u[3] * w2[3];
                        emitl(j, acc);
                    }
                }
            } else {
                float w[23];
#pragma unroll
                for (int p = 0; p < 23; ++p) w[p] = w3_0e[(s * 23 + p) * CC + c];
                if (q == 0)      dopairs<0, 12, 23>(uls, w, myrow);
                else if (q == 1) dopairs<12, 24, 23>(uls, w, myrow);
                else if (q == 2) dopairs<24, 35, 23>(uls, w, myrow);
                else             dopairs<35, 45, 23>(uls, w, myrow);
                if (q == 3) {
                    float w2[4];
#pragma unroll
                    for (int p = 0; p < 4; ++p) w2[p] = w2_0e[(s * 4 + p) * CC + c];
#pragma unroll
                    for (int j = 0; j < 9; ++j) {
                        const float* u = u2_0e + (size_t)((i * 9 + j)) * 4;
                        float acc = u[0] * w2[0] + u[1] * w2[1] + u[2] * w2[2] + u[3] * w2[3];
                        emitl(j, acc);
                    }
                }
            }
        } else if (idx == 9 && q == 0) {
            if (sec < 3) {
                float wv = w1_1o[s * CC + c];
#pragma unroll
                for (int i = 0; i < 9; ++i) emitl(i, u1_1o[sec * 9 + i] * wv);
            } else {
                float wv = w1_0e[s * CC + c];
#pragma unroll
                for (int i = 0; i < 9; ++i) emitl(i, u1_0e[i] * wv);
            }
        }
        __syncthreads();   // fence before typed readback (R10 TBAA lesson)
        int blk = row >> 4, r16 = row & 15;
#pragma unroll 1
        for (int j = t; j < 1536; j += 512) {
            int c2 = j / 12, chunk = j % 12;
            int h = chunk >> 2, g = chunk & 3;
            uint4 v = *(uint4*)&rowbuf[c2 * 48 + chunk * 4];
            u16* dst = af + (size_t)(c2 * SS + s) * AFRAG_U16
                          + (size_t)((blk * 3 + h) * 64 + g * 16 + r16) * 8;
            *(uint4*)dst = v;
        }
        return;
    }
    // ---- prepf: 2 sub-blocks per block ----
    {
        int b = (bid - (SC_BLK + P2_BLK)) * 2 + (t >> 8);   // 0..175
        int tl = t & 255;
        int lane = tl & 63, ck = tl >> 6;
        if (b < 160) {
            int s = b >> 4, kt = b & 15;
            int k = kt * 16 + (lane & 15);
            u16* dst = gkf + (((size_t)b * 4 + ck) * 64 + lane) * 8;
            const float* src = gk + (size_t)s * CC * 256;
#pragma unroll
            for (int e = 0; e < 8; ++e) {
                int c = ck * 32 + ((lane >> 4) & 3) * 8 + e;
                dst[e] = bf16rne(src[c * 256 + k]);
            }
        } else {
            int bb = b - 160;
            int kt = bb & 7;
            int k = kt * 16 + (lane & 15);
            const float* src = (bb >> 3) ? lin1 : lin0;
            u16* dst = linf + (((size_t)bb * 4 + ck) * 64 + lane) * 8;
#pragma unroll
            for (int e = 0; e < 8; ++e) {
                int c = ck * 32 + ((lane >> 4) & 3) * 8 + e;
                dst[e] = bf16rne(src[c * CC + k]);
            }
        }
    }
}

// ---------------- xpose: nf -> xt[c][pos][16] bf16, sorted positions ----------
#define XROW 577   // uint stride per row (576 would be 16-way bank conflict)
__global__ __launch_bounds__(256) void k_xpose(
    const float* __restrict__ nf, const int* __restrict__ order,
    const int* __restrict__ blk_sp, const int* __restrict__ vend,
    u16* __restrict__ xt) {
    __shared__ uint rows[16 * XROW];   // 36.9 KB
    __shared__ int ords[16];
    int pos0 = blockIdx.x * 16;
    int seg = pos0 / NPB;
    int s = blk_sp[seg];
    int lim = seg * NPB + ((s >= 0) ? vend[seg] : 0);
    int t = threadIdx.x;

    if (t < 16) ords[t] = (pos0 + t < lim) ? order[pos0 + t] : -1;
    __syncthreads();

#pragma unroll 1
    for (int i = t; i < 4608; i += 256) {
        int r = i / 288, j = i % 288;
        int n = ords[r];
        uint2 pk = {0u, 0u};
        if (n >= 0) {
            float4 v = *(const float4*)(nf + (size_t)n * 1152 + j * 4);
            pk.x = pk2(v.x, v.y);
            pk.y = pk2(v.z, v.w);
        }
        *(uint2*)&rows[r * XROW + j * 2] = pk;
    }
    __syncthreads();

    auto elem = [&](int r, int e) -> uint {
        uint w = rows[r * XROW + (e >> 1)];
        return (e & 1) ? (w >> 16) : (w & 0xffffu);
    };
#pragma unroll 1
    for (int i = t; i < 2048; i += 256) {
        int c = i >> 4, r = i & 15;
        uint x0 = elem(r, c);
        uint x1 = elem(r, 128 + c * 3), x2 = elem(r, 128 + c * 3 + 1), x3 = elem(r, 128 + c * 3 + 2);
        uint x4 = elem(r, 512 + c * 5), x5 = elem(r, 512 + c * 5 + 1);
        uint x6 = elem(r, 512 + c * 5 + 2), x7 = elem(r, 512 + c * 5 + 3), x8 = elem(r, 512 + c * 5 + 4);
        uint4 lo = {x0 | (x1 << 16), x2 | (x3 << 16), x4 | (x5 << 16), x6 | (x7 << 16)};
        u16* dst = xt + ((size_t)c * NPAD + pos0 + r) * 16;
        *(uint4*)dst = lo;
        *(uint*)(dst + 8) = x8;
    }
}

// ---------------- symmetric contraction via MFMA (coalesced xt reads) ----------
__global__ __launch_bounds__(128) void k_contract(
    const u16* __restrict__ xt, const int* __restrict__ blk_sp,
    const u16* __restrict__ af_g,
    float* __restrict__ f0t, float* __restrict__ f1t) {
    int bid = blockIdx.x;                 // 0..5119
    int xcd = bid & 7;
    int r = bid >> 3;
    int c = xcd * 16 + (r / 40);
    int t2 = r % 40;
    int seg = t2 >> 1, half = t2 & 1;
    int s = blk_sp[seg];
    if (s < 0) return;

    int tid = threadIdx.x;
    int lane = tid & 63;
    int wq = half * 2 + (tid >> 6);
    int n16 = lane & 15, gg = lane >> 4;

    const bf16x8* ab = (const bf16x8*)(af_g + (size_t)(c * SS + s) * AFRAG_U16);
    bf16x8 a00 = ab[0 * 64 + lane], a01 = ab[1 * 64 + lane], a02 = ab[2 * 64 + lane];
    bf16x8 a10 = ab[3 * 64 + lane], a11 = ab[4 * 64 + lane], a12 = ab[5 * 64 + lane];
    bf16x8 a20 = ab[6 * 64 + lane], a21 = ab[7 * 64 + lane], a22 = ab[8 * 64 + lane];

    int posw = seg * NPB + wq * 16 + n16;
    const u16* xp = xt + (size_t)c * NPAD * 16;

    uint4 qa = *(const uint4*)&xp[(size_t)posw * 16];
    uint  ha = *(const uint*)&xp[(size_t)posw * 16 + 8];
    uint4 qb = *(const uint4*)&xp[(size_t)(posw + 64) * 16];
    uint  hb = *(const uint*)&xp[(size_t)(posw + 64) * 16 + 8];

#pragma unroll 1
    for (int sub = 0; sub < 16; ++sub) {
        uint4 qf = {0u, 0u, 0u, 0u}; uint hf = 0u;
        if (sub < 14) {
            qf = *(const uint4*)&xp[(size_t)(posw + (sub + 2) * 64) * 16];
            hf = *(const uint*)&xp[(size_t)(posw + (sub + 2) * 64) * 16 + 8];
        }

        float xc0 = __uint_as_float(qa.x << 16), xc1 = __uint_as_float(qa.x & 0xffff0000u);
        float xc2 = __uint_as_float(qa.y << 16), xc3 = __uint_as_float(qa.y & 0xffff0000u);
        float xc4 = __uint_as_float(qa.z << 16), xc5 = __uint_as_float(qa.z & 0xffff0000u);
        float xc6 = __uint_as_float(qa.w << 16), xc7 = __uint_as_float(qa.w & 0xffff0000u);
        float xc8 = __uint_as_float(ha << 16);

        float xa0 = (gg == 0) ? xc0 : (gg == 1) ? xc1 : (gg == 2) ? xc2 : xc3;
        float xa1 = (gg == 0) ? xc4 : (gg == 1) ? xc5 : (gg == 2) ? xc6 : xc7;
        float xa2 = (gg == 0) ? xc8 : (gg == 1) ? 1.0f : (gg == 2) ? xc6 : xc7;
        uint4 q0, q1, q2;
        q0.x = pk2(xa0 * xc0, xa0 * xc1);
        q0.y = pk2(xa0 * xc2, xa0 * xc3);
        q0.z = pk2(xa0 * xc4, xa0 * xc5);
        q0.w = pk2(xa0 * xc6, xa0 * xc7);
        q1.x = pk2(xa1 * xc0, xa1 * xc1);
        q1.y = pk2(xa1 * xc2, xa1 * xc3);
        q1.z = pk2(xa1 * xc4, xa1 * xc5);
        q1.w = pk2(xa1 * xc6, xa1 * xc7);
        q2.x = pk2(xa2 * xc8, xa2);
        q2.y = pk2(xa2 * xc0, xa2 * xc1);
        q2.z = pk2(xa2 * xc2, xa2 * xc3);
        q2.w = pk2(xa2 * xc4, xa2 * xc5);
        bf16x8 y0 = __builtin_bit_cast(bf16x8, q0);
        bf16x8 y1 = __builtin_bit_cast(bf16x8, q1);
        bf16x8 y2 = __builtin_bit_cast(bf16x8, q2);

        f32x4 acc0 = {0.f, 0.f, 0.f, 0.f}, acc1 = acc0, acc2 = acc0;
        acc0 = __builtin_amdgcn_mfma_f32_16x16x32_bf16(a00, y0, acc0, 0, 0, 0);
        acc0 = __builtin_amdgcn_mfma_f32_16x16x32_bf16(a01, y1, acc0, 0, 0, 0);
        acc0 = __builtin_amdgcn_mfma_f32_16x16x32_bf16(a02, y2, acc0, 0, 0, 0);
        acc1 = __builtin_amdgcn_mfma_f32_16x16x32_bf16(a10, y0, acc1, 0, 0, 0);
        acc1 = __builtin_amdgcn_mfma_f32_16x16x32_bf16(a11, y1, acc1, 0, 0, 0);
        acc1 = __builtin_amdgcn_mfma_f32_16x16x32_bf16(a12, y2, acc1, 0, 0, 0);
        acc2 = __builtin_amdgcn_mfma_f32_16x16x32_bf16(a20, y0, acc2, 0, 0, 0);
        acc2 = __builtin_amdgcn_mfma_f32_16x16x32_bf16(a21, y1, acc2, 0, 0, 0);
        acc2 = __builtin_amdgcn_mfma_f32_16x16x32_bf16(a22, y2, acc2, 0, 0, 0);

        f32x4 eA = (gg == 0) ? acc0 : (gg == 1) ? acc2 : (gg == 2) ? acc1 : acc0;
        f32x4 eB = (gg == 0) ? acc1 : (gg == 1) ? acc0 : (gg == 2) ? acc2 : acc1;
        f32x4 eC = (gg == 0) ? acc2 : (gg == 1) ? acc1 : (gg == 2) ? acc0 : acc2;
        float dA = eA[0] * xc0 + eA[1] * xc1 + eA[2] * xc2 + eA[3] * xc3;
        float dB = eB[0] * xc4 + eB[1] * xc5 + eB[2] * xc6 + eB[3] * xc7;
        float dC = eC[0] * xc8 + eC[1];
        float p0 = (gg == 0) ? dA : (gg == 1) ? dB : (gg == 2) ? dC : 0.f;
        float p1 = (gg == 0) ? dB : (gg == 1) ? dC : (gg == 2) ? 0.f : dA;
        float p2 = (gg == 0) ? dC : (gg == 1) ? 0.f : (gg == 2) ? dA : dB;
        float p3 = (gg == 0) ? 0.f : (gg == 1) ? dA : (gg == 2) ? dB : dC;
        p0 += __shfl_xor(p0, 16); p1 += __shfl_xor(p1, 16);
        p2 += __shfl_xor(p2, 16); p3 += __shfl_xor(p3, 16);
        p0 += __shfl_xor(p0, 32); p1 += __shfl_xor(p1, 32);
        p2 += __shfl_xor(p2, 32); p3 += __shfl_xor(p3, 32);
        float val = (gg == 0) ? p0 : (gg == 1) ? p1 : (gg == 2) ? p2 : p3;

        int pos = posw + sub * 64;
        if (gg == 3) f0t[(size_t)c * NPAD + pos] = val;
        else         f1t[(size_t)(c * 3 + gg) * NPAD + pos] = val;

        qa = qb; ha = hb; qb = qf; hb = hf;
    }
}

// ---------------- fused gate + equivariant linear (MFMA), 2-way split ----------
#define GSTR 264
__global__ __launch_bounds__(256) void k_post(
    const float* __restrict__ f0t, const float* __restrict__ f1t,
    const u16* __restrict__ gkf, const u16* __restrict__ linf,
    const float* __restrict__ gb, const int* __restrict__ order,
    const int* __restrict__ blk_sp, const int* __restrict__ vend,
    float* __restrict__ out) {
    int tile = blockIdx.x;
    int half = blockIdx.y;
    int s = blk_sp[tile >> 4];
    if (s < 0) return;
    int p0 = tile * 64;
    int vv = vend[tile >> 4];
    int boff = (tile & 15) * 64;

    __shared__ __align__(16) u16 frag[4][4][64][8];
    __shared__ __align__(16) u16 gate_l[64 * GSTR];
    __shared__ int ord[64];

    int t = threadIdx.x, lane = t & 63, w = t >> 6;
    int l15 = lane & 15, lg = lane >> 4;
    if (t < 64) ord[t] = (boff + t < vv) ? order[p0 + t] : -1;

#pragma unroll 1
    for (int it = 0; it < 32; ++it) {
        int posn = t & 63;
        int c = (t >> 6) + 4 * it;
        float v = f0t[(size_t)c * NPAD + p0 + posn];
        frag[posn >> 4][c >> 5][((c >> 3) & 3) * 16 + (posn & 15)][c & 7] = bf16rne(v);
    }
    __syncthreads();

#pragma unroll 1
    for (int kt = 0; kt < 16; ++kt) {
        float bias = gb[s * 256 + kt * 16 + l15];
        f32x4 acc = {bias, bias, bias, bias};
#pragma unroll
        for (int ck = 0; ck < 4; ++ck) {
            bf16x8 a = *(const bf16x8*)&frag[w][ck][lane][0];
            bf16x8 b = *(const bf16x8*)&gkf[(((size_t)(s * 16 + kt)) * 4 + ck) * 512 + lane * 8];
            acc = __builtin_amdgcn_mfma_f32_16x16x32_bf16(a, b, acc, 0, 0, 0);
        }
#pragma unroll
        for (int r = 0; r < 4; ++r) {
            int posn = w * 16 + lg * 4 + r;
            gate_l[posn * GSTR + kt * 16 + l15] = bf16rne(acc[r]);
        }
    }
    __syncthreads();

    const float INV = 0.08838834764831845f;   // 1/sqrt(128)

#pragma unroll 1
    for (int p = 2 * half; p < 2 * half + 2; ++p) {
#pragma unroll 1
        for (int it = 0; it < 4; ++it) {
            int rr = it * 256 + t;
            int pt = rr >> 8, ck = (rr >> 6) & 3, l2 = rr & 63;
            int posn = pt * 16 + (l2 & 15);
            int cb = ck * 32 + (l2 >> 4) * 8;
            u16 res[8];
            if (p == 0) {
                bf16x8 a1 = *(const bf16x8*)&frag[pt][ck][l2][0];
                const u16* gp = &gate_l[posn * GSTR + cb];
#pragma unroll
                for (int e = 0; e < 8; ++e)
                    res[e] = bf16rne(bf2f((u16)a1[e]) * bf2f(gp[e]));
            } else {
                int z = p - 1;
                const u16* gp = &gate_l[posn * GSTR + 128 + cb];
#pragma unroll
                for (int e = 0; e < 8; ++e) {
                    float fv = f1t[((size_t)(cb + e) * 3 + z) * NPAD + p0 + posn];
                    res[e] = bf16rne(fv * bf2f(gp[e]));
                }
            }
            uint4 uv;
            uv.x = (unsigned)res[0] | ((unsigned)res[1] << 16);
            uv.y = (unsigned)res[2] | ((unsigned)res[3] << 16);
            uv.z = (unsigned)res[4] | ((unsigned)res[5] << 16);
            uv.w = (unsigned)res[6] | ((unsigned)res[7] << 16);
            *(uint4*)&frag[pt][ck][l2][0] = uv;
        }
        __syncthreads();

        int lbase = (p == 0) ? 0 : 8;
#pragma unroll 1
        for (int kt = 0; kt < 8; ++kt) {
            f32x4 acc = {0.f, 0.f, 0.f, 0.f};
#pragma unroll
            for (int ck = 0; ck < 4; ++ck) {
                bf16x8 a = *(const bf16x8*)&frag[w][ck][lane][0];
                bf16x8 b = *(const bf16x8*)&linf[(((size_t)(lbase + kt)) * 4 + ck) * 512 + lane * 8];
                acc = __builtin_amdgcn_mfma_f32_16x16x32_bf16(a, b, acc, 0, 0, 0);
            }
            int k = kt * 16 + l15;
            int kk = (p == 0) ? k : (128 + k * 3 + (p - 1));
#pragma unroll
            for (int r = 0; r < 4; ++r) {
                int posn = w * 16 + lg * 4 + r;
                int n = ord[posn];
                if (n >= 0) out[(size_t)n * 512 + kk] = acc[r] * INV;
            }
        }
        __syncthreads();
    }
}

// ---------------------------------------------------------------------------
extern "C" void kernel_launch(void* const* d_in, const int* in_sizes, int n_in,
                              void* d_out, int out_size, void* d_ws, size_t ws_size,
                              hipStream_t stream) {
    const float* nf    = (const float*)d_in[0];
    const int*   sp    = (const int*)  d_in[1];
    const float* u1_0e = (const float*)d_in[2];
    const float* u2_0e = (const float*)d_in[3];
    const float* u3_0e = (const float*)d_in[4];
    const float* u1_1o = (const float*)d_in[5];
    const float* u2_1o = (const float*)d_in[6];
    const float* u3_1o = (const float*)d_in[7];
    const float* w1_0e = (const float*)d_in[8];
    const float* w2_0e = (const float*)d_in[9];
    const float* w3_0e = (const float*)d_in[10];
    const float* w1_1o = (const float*)d_in[11];
    const float* w2_1o = (const float*)d_in[12];
    const float* w3_1o = (const float*)d_in[13];
    const float* gk    = (const float*)d_in[14];
    const float* gb    = (const float*)d_in[15];
    const float* lin0  = (const float*)d_in[16];
    const float* lin1  = (const float*)d_in[17];

    float* ws   = (float*)d_ws;
    u16*  af    = (u16*)(ws + OFF_AF);
    float* f0t  = ws + OFF_F0;
    float* f1t  = ws + OFF_F1;
    u16*  gkf   = (u16*)(ws + OFF_GKF);
    u16*  linf  = (u16*)(ws + OFF_LINF);
    int* order  = (int*)(ws + OFF_ORD);
    int* meta   = (int*)(ws + OFF_META);
    u16*  xt    = (u16*)(ws + OFF_XT);
    int* cursor = meta + 16;
    int* blk_sp = meta + 32;
    int* vend   = meta + 64;

    k_plan<<<1, 256, 0, stream>>>(sp, cursor, blk_sp, vend);
    k_setup2<<<SC_BLK + P2_BLK + 88, 512, 0, stream>>>(
        sp, cursor, order,
        u1_0e, u2_0e, u3_0e, u1_1o, u2_1o, u3_1o,
        w1_0e, w2_0e, w3_0e, w1_1o, w2_1o, w3_1o, af,
        gk, lin0, lin1, gkf, linf);
    k_xpose<<<NPAD / 16, 256, 0, stream>>>(nf, order, blk_sp, vend, xt);
    k_contract<<<5120, 128, 0, stream>>>(xt, blk_sp, af, f0t, f1t);
    dim3 gpost(NPAD / 64, 2);
    k_post<<<gpost, 256, 0, stream>>>(f0t, f1t, gkf, linf, gb, order, blk_sp, vend,
                                      (float*)d_out);
}

// Round 23
// 122.774 us; speedup vs baseline: 1.2775x; 1.0868x over previous
//
#include <hip/hip_runtime.h>

// ---------------------------------------------------------------------------
// EquivariantProductBasisBlock (MACE symmetric contraction + gate + linear)
// N=10000, C=128, D=9, S=10.
// R23 = R22 with xt split into DENSE arrays: xt8[c][pos] (16B: x0..x7) +
// xt1[c][pos] (4B: x8). R22's 32B records had 12B pad -> partial-line HBM
// writes -> RMW amplification (WRITE 82MB for 52MB payload + 22MB RMW fetch).
// Dense lines kill the RMW. Contract reads dwordx4 + dword. ws 138->107MB.
// ---------------------------------------------------------------------------

#define NN 10000
#define CC 128
#define SS 10
#define NPB 1024
#define MAXBLK 20
#define NPAD (MAXBLK*NPB)        // 20480

typedef unsigned short u16;
typedef unsigned int uint;
typedef __attribute__((ext_vector_type(8))) short bf16x8;
typedef __attribute__((ext_vector_type(4))) float f32x4;

#define AFRAG_U16 4608

// ws layout (floats)
#define OFF_AF   0                          // 1280*4608 u16 = 2,949,120 f
#define OFF_F0   2949120                    // CC*NPAD   = 2,621,440
#define OFF_F1   5570560                    // 3*CC*NPAD = 7,864,320
#define OFF_GKF  13434880                   // 327,680 u16 = 163,840 f
#define OFF_LINF 13598720                   // 32,768 u16 = 16,384 f
#define OFF_ORD  13615104                   // NPAD ints
#define OFF_META 13635584                   // 128 ints
#define OFF_XT8  13635712                   // NPAD*CC*8 u16 = 10,485,760 f
#define OFF_XT1  24121472                   // NPAD*CC uint  = 2,621,440 f
// total = 26,742,912 floats = 107 MB

constexpr int cPA[45] = {
    0,0,0,0,0,0,0,0,0, 1,1,1,1,1,1,1,1, 2,2,2,2,2,2,2,
    3,3,3,3,3,3, 4,4,4,4,4, 5,5,5,5, 6,6,6, 7,7, 8};
constexpr int cPB[45] = {
    0,1,2,3,4,5,6,7,8, 1,2,3,4,5,6,7,8, 2,3,4,5,6,7,8,
    3,4,5,6,7,8, 4,5,6,7,8, 5,6,7,8, 6,7,8, 7,8, 8};

__device__ __forceinline__ u16 bf16rne(float f) {
    unsigned u = __float_as_uint(f);
    u += 0x7fffu + ((u >> 16) & 1u);
    return (u16)(u >> 16);
}
__device__ __forceinline__ float bf2f(u16 h) {
    return __uint_as_float(((unsigned)h) << 16);
}
__device__ __forceinline__ unsigned pk2(float lo, float hi) {
    unsigned r;
    asm("v_cvt_pk_bf16_f32 %0, %1, %2" : "=v"(r) : "v"(lo), "v"(hi));
    return r;
}

// fully-unrolled pair range [KA,KB) with P-length dots; all offsets fold.
template<int KA, int KB, int P>
__device__ __forceinline__ void dopairs(const float* __restrict__ uls,
                                        const float* __restrict__ w,
                                        u16* __restrict__ myrow) {
#pragma unroll
    for (int k = KA; k < KB; ++k) {
        const int a = cPA[k], b = cPB[k];
        float acc = 0.f;
        if (a == b) {
#pragma unroll
            for (int p = 0; p < P; ++p) acc += uls[(a * 9 + b) * P + p] * w[p];
        } else {
#pragma unroll
            for (int p = 0; p < P; ++p)
                acc += (uls[(a * 9 + b) * P + p] + uls[(b * 9 + a) * P + p]) * w[p];
        }
        int h, g, e;
        if (b == 8) {
            if (a == 8)      { h = 2; g = 0; e = 0; }
            else if (a <= 5) { h = 2; g = 0; e = 2 + a; }
            else if (a == 6) { h = 2; g = 2; e = 0; }
            else             { h = 2; g = 3; e = 0; }
        } else if (a < 4)    { h = 0; g = a; e = b; }
        else                 { h = 1; g = a - 4; e = b; }
        myrow[(h * 4 + g) * 8 + e] = bf16rne(acc);
    }
}

// ---------------- plan: hist + segment map + vend (1 block) ----------------
__global__ __launch_bounds__(256) void k_plan(
    const int* __restrict__ sp, int* __restrict__ cursor,
    int* __restrict__ blk_sp, int* __restrict__ vend) {
    __shared__ int cnt[SS];
    int t = threadIdx.x;
    if (t < SS) cnt[t] = 0;
    __syncthreads();
    for (int i = t; i < NN; i += 256) atomicAdd(&cnt[sp[i]], 1);
    __syncthreads();
    if (t == 0) {
        int pos = 0, b = 0;
        for (int s = 0; s < SS; ++s) {
            cursor[s] = pos;
            int nb = (cnt[s] + NPB - 1) / NPB;
            for (int i = 0; i < nb; ++i) {
                blk_sp[b] = s;
                int rem = cnt[s] - i * NPB;
                vend[b] = rem > NPB ? NPB : rem;
                ++b;
            }
            pos += nb * NPB;
        }
        for (; b < MAXBLK; ++b) { blk_sp[b] = -1; vend[b] = 0; }
    }
}

// ---------------- fused setup: scatter | prep2 | prepf (512 thr) ----------------
#define SC_BLK 20
#define P2_BLK 480
__global__ __launch_bounds__(512) void k_setup2(
    const int* __restrict__ sp, int* __restrict__ cursor, int* __restrict__ order,
    const float* __restrict__ u1_0e, const float* __restrict__ u2_0e, const float* __restrict__ u3_0e,
    const float* __restrict__ u1_1o, const float* __restrict__ u2_1o, const float* __restrict__ u3_1o,
    const float* __restrict__ w1_0e, const float* __restrict__ w2_0e, const float* __restrict__ w3_0e,
    const float* __restrict__ w1_1o, const float* __restrict__ w2_1o, const float* __restrict__ w3_1o,
    u16* __restrict__ af,
    const float* __restrict__ gk, const float* __restrict__ lin0,
    const float* __restrict__ lin1, u16* __restrict__ gkf, u16* __restrict__ linf) {
    __shared__ __align__(16) uint rowbuf[128 * 48];   // 24.6 KB
    __shared__ __align__(16) float uls[2430];         // 9.7 KB (u3 slice)
    __shared__ int lcnt[SS];
    __shared__ int gbase[SS];
    int bid = blockIdx.x, t = threadIdx.x;

    if (bid < SC_BLK) {
        // ---- scatter with per-block pre-aggregation (Guideline 12) ----
        if (t < SS) lcnt[t] = 0;
        __syncthreads();
        int n = bid * 512 + t;
        int mys = -1, myrank = 0;
        if (n < NN) {
            mys = sp[n];
            myrank = atomicAdd(&lcnt[mys], 1);     // LDS atomic (fast)
        }
        __syncthreads();
        if (t < SS && lcnt[t] > 0) gbase[t] = atomicAdd(&cursor[t], lcnt[t]);
        __syncthreads();
        if (n < NN) order[gbase[mys] + myrank] = n;
        return;
    }
    if (bid < SC_BLK + P2_BLK) {
        int b2 = bid - SC_BLK;
        int row = b2 % 48, s = b2 / 48;
        int c = t & 127, q = t >> 7;            // q wave-uniform
        int sec = row / 12, idx = row % 12;
        u16* myrow = (u16*)&rowbuf[c * 48];
        for (int i = t; i < 128 * 48; i += 512) rowbuf[i] = 0u;
        if (idx < 9) {
            if (sec < 3) {
                const float* src = u3_1o + (size_t)(sec * 9 + idx) * 2430;
                for (int j = t; j < 2430; j += 512) uls[j] = src[j];
            } else {
                const float* src = u3_0e + (size_t)idx * 1863;
                for (int j = t; j < 1863; j += 512) uls[j] = src[j];
            }
        }
        __syncthreads();

        auto emitl = [&](int j, float v) {
            int h, g, e;
            if (j == 8)      { h = 2; g = 0; e = 1; }
            else if (j <= 5) { h = 2; g = 1; e = 2 + j; }
            else if (j == 6) { h = 2; g = 2; e = 1; }
            else             { h = 2; g = 3; e = 1; }
            myrow[(h * 4 + g) * 8 + e] = bf16rne(v);
        };
        if (idx < 9) {
            int i = idx;
            if (sec < 3) {
                float w[30];
#pragma unroll
                for (int p = 0; p < 30; ++p) w[p] = w3_1o[(s * 30 + p) * CC + c];
                if (q == 0)      dopairs<0, 12, 30>(uls, w, myrow);
                else if (q == 1) dopairs<12, 24, 30>(uls, w, myrow);
                else if (q == 2) dopairs<24, 35, 30>(uls, w, myrow);
                else             dopairs<35, 45, 30>(uls, w, myrow);
                if (q == 3) {
                    float w2[4];
#pragma unroll
                    for (int p = 0; p < 4; ++p) w2[p] = w2_1o[(s * 4 + p) * CC + c];
#pragma unroll
                    for (int j = 0; j < 9; ++j) {
                        const float* u = u2_1o + (size_t)(((sec * 9 + i) * 9 + j)) * 4;
                        float acc = u[0] * w2[0] + u[1] * w2[1] + u[2] * w2[2] + u[3] * w2[3];
                        emitl(j, acc);
                    }
                }
            } else {
                float w[23];
#pragma unroll
                for (int p = 0; p < 23; ++p) w[p] = w3_0e[(s * 23 + p) * CC + c];
                if (q == 0)      dopairs<0, 12, 23>(uls, w, myrow);
                else if (q == 1) dopairs<12, 24, 23>(uls, w, myrow);
                else if (q == 2) dopairs<24, 35, 23>(uls, w, myrow);
                else             dopairs<35, 45, 23>(uls, w, myrow);
                if (q == 3) {
                    float w2[4];
#pragma unroll
                    for (int p = 0; p < 4; ++p) w2[p] = w2_0e[(s * 4 + p) * CC + c];
#pragma unroll
                    for (int j = 0; j < 9; ++j) {
                        const float* u = u2_0e + (size_t)((i * 9 + j)) * 4;
                        float acc = u[0] * w2[0] + u[1] * w2[1] + u[2] * w2[2] + u[3] * w2[3];
                        emitl(j, acc);
                    }
                }
            }
        } else if (idx == 9 && q == 0) {
            if (sec < 3) {
                float wv = w1_1o[s * CC + c];
#pragma unroll
                for (int i = 0; i < 9; ++i) emitl(i, u1_1o[sec * 9 + i] * wv);
            } else {
                float wv = w1_0e[s * CC + c];
#pragma unroll
                for (int i = 0; i < 9; ++i) emitl(i, u1_0e[i] * wv);
            }
        }
        __syncthreads();   // fence before typed readback (R10 TBAA lesson)
        int blk = row >> 4, r16 = row & 15;
#pragma unroll 1
        for (int j = t; j < 1536; j += 512) {
            int c2 = j / 12, chunk = j % 12;
            int h = chunk >> 2, g = chunk & 3;
            uint4 v = *(uint4*)&rowbuf[c2 * 48 + chunk * 4];
            u16* dst = af + (size_t)(c2 * SS + s) * AFRAG_U16
                          + (size_t)((blk * 3 + h) * 64 + g * 16 + r16) * 8;
            *(uint4*)dst = v;
        }
        return;
    }
    // ---- prepf: 2 sub-blocks per block ----
    {
        int b = (bid - (SC_BLK + P2_BLK)) * 2 + (t >> 8);   // 0..175
        int tl = t & 255;
        int lane = tl & 63, ck = tl >> 6;
        if (b < 160) {
            int s = b >> 4, kt = b & 15;
            int k = kt * 16 + (lane & 15);
            u16* dst = gkf + (((size_t)b * 4 + ck) * 64 + lane) * 8;
            const float* src = gk + (size_t)s * CC * 256;
#pragma unroll
            for (int e = 0; e < 8; ++e) {
                int c = ck * 32 + ((lane >> 4) & 3) * 8 + e;
                dst[e] = bf16rne(src[c * 256 + k]);
            }
        } else {
            int bb = b - 160;
            int kt = bb & 7;
            int k = kt * 16 + (lane & 15);
            const float* src = (bb >> 3) ? lin1 : lin0;
            u16* dst = linf + (((size_t)bb * 4 + ck) * 64 + lane) * 8;
#pragma unroll
            for (int e = 0; e < 8; ++e) {
                int c = ck * 32 + ((lane >> 4) & 3) * 8 + e;
                dst[e] = bf16rne(src[c * CC + k]);
            }
        }
    }
}

// ---------------- xpose: nf -> xt8[c][pos] (16B) + xt1[c][pos] (4B) ----------
#define XROW 577   // uint stride per row (576 would be 16-way bank conflict)
__global__ __launch_bounds__(256) void k_xpose(
    const float* __restrict__ nf, const int* __restrict__ order,
    const int* __restrict__ blk_sp, const int* __restrict__ vend,
    u16* __restrict__ xt8, uint* __restrict__ xt1) {
    __shared__ uint rows[16 * XROW];   // 36.9 KB
    __shared__ int ords[16];
    int pos0 = blockIdx.x * 16;
    int seg = pos0 / NPB;
    int s = blk_sp[seg];
    int lim = seg * NPB + ((s >= 0) ? vend[seg] : 0);
    int t = threadIdx.x;

    if (t < 16) ords[t] = (pos0 + t < lim) ? order[pos0 + t] : -1;
    __syncthreads();

#pragma unroll 1
    for (int i = t; i < 4608; i += 256) {
        int r = i / 288, j = i % 288;
        int n = ords[r];
        uint2 pk = {0u, 0u};
        if (n >= 0) {
            float4 v = *(const float4*)(nf + (size_t)n * 1152 + j * 4);
            pk.x = pk2(v.x, v.y);
            pk.y = pk2(v.z, v.w);
        }
        *(uint2*)&rows[r * XROW + j * 2] = pk;
    }
    __syncthreads();

    auto elem = [&](int r, int e) -> uint {
        uint w = rows[r * XROW + (e >> 1)];
        return (e & 1) ? (w >> 16) : (w & 0xffffu);
    };
#pragma unroll 1
    for (int i = t; i < 2048; i += 256) {
        int c = i >> 4, r = i & 15;
        uint x0 = elem(r, c);
        uint x1 = elem(r, 128 + c * 3), x2 = elem(r, 128 + c * 3 + 1), x3 = elem(r, 128 + c * 3 + 2);
        uint x4 = elem(r, 512 + c * 5), x5 = elem(r, 512 + c * 5 + 1);
        uint x6 = elem(r, 512 + c * 5 + 2), x7 = elem(r, 512 + c * 5 + 3), x8 = elem(r, 512 + c * 5 + 4);
        uint4 lo = {x0 | (x1 << 16), x2 | (x3 << 16), x4 | (x5 << 16), x6 | (x7 << 16)};
        *(uint4*)&xt8[((size_t)c * NPAD + pos0 + r) * 8] = lo;
        xt1[(size_t)c * NPAD + pos0 + r] = x8;
    }
}

// ---------------- symmetric contraction via MFMA (dense xt reads) ----------
__global__ __launch_bounds__(128) void k_contract(
    const u16* __restrict__ xt8, const uint* __restrict__ xt1,
    const int* __restrict__ blk_sp, const u16* __restrict__ af_g,
    float* __restrict__ f0t, float* __restrict__ f1t) {
    int bid = blockIdx.x;                 // 0..5119
    int xcd = bid & 7;
    int r = bid >> 3;
    int c = xcd * 16 + (r / 40);
    int t2 = r % 40;
    int seg = t2 >> 1, half = t2 & 1;
    int s = blk_sp[seg];
    if (s < 0) return;

    int tid = threadIdx.x;
    int lane = tid & 63;
    int wq = half * 2 + (tid >> 6);
    int n16 = lane & 15, gg = lane >> 4;

    const bf16x8* ab = (const bf16x8*)(af_g + (size_t)(c * SS + s) * AFRAG_U16);
    bf16x8 a00 = ab[0 * 64 + lane], a01 = ab[1 * 64 + lane], a02 = ab[2 * 64 + lane];
    bf16x8 a10 = ab[3 * 64 + lane], a11 = ab[4 * 64 + lane], a12 = ab[5 * 64 + lane];
    bf16x8 a20 = ab[6 * 64 + lane], a21 = ab[7 * 64 + lane], a22 = ab[8 * 64 + lane];

    int posw = seg * NPB + wq * 16 + n16;
    const u16* xp8 = xt8 + (size_t)c * NPAD * 8;
    const uint* xp1 = xt1 + (size_t)c * NPAD;

    uint4 qa = *(const uint4*)&xp8[(size_t)posw * 8];
    uint  ha = xp1[posw];
    uint4 qb = *(const uint4*)&xp8[(size_t)(posw + 64) * 8];
    uint  hb = xp1[posw + 64];

#pragma unroll 1
    for (int sub = 0; sub < 16; ++sub) {
        uint4 qf = {0u, 0u, 0u, 0u}; uint hf = 0u;
        if (sub < 14) {
            qf = *(const uint4*)&xp8[(size_t)(posw + (sub + 2) * 64) * 8];
            hf = xp1[posw + (sub + 2) * 64];
        }

        float xc0 = __uint_as_float(qa.x << 16), xc1 = __uint_as_float(qa.x & 0xffff0000u);
        float xc2 = __uint_as_float(qa.y << 16), xc3 = __uint_as_float(qa.y & 0xffff0000u);
        float xc4 = __uint_as_float(qa.z << 16), xc5 = __uint_as_float(qa.z & 0xffff0000u);
        float xc6 = __uint_as_float(qa.w << 16), xc7 = __uint_as_float(qa.w & 0xffff0000u);
        float xc8 = __uint_as_float(ha << 16);

        float xa0 = (gg == 0) ? xc0 : (gg == 1) ? xc1 : (gg == 2) ? xc2 : xc3;
        float xa1 = (gg == 0) ? xc4 : (gg == 1) ? xc5 : (gg == 2) ? xc6 : xc7;
        float xa2 = (gg == 0) ? xc8 : (gg == 1) ? 1.0f : (gg == 2) ? xc6 : xc7;
        uint4 q0, q1, q2;
        q0.x = pk2(xa0 * xc0, xa0 * xc1);
        q0.y = pk2(xa0 * xc2, xa0 * xc3);
        q0.z = pk2(xa0 * xc4, xa0 * xc5);
        q0.w = pk2(xa0 * xc6, xa0 * xc7);
        q1.x = pk2(xa1 * xc0, xa1 * xc1);
        q1.y = pk2(xa1 * xc2, xa1 * xc3);
        q1.z = pk2(xa1 * xc4, xa1 * xc5);
        q1.w = pk2(xa1 * xc6, xa1 * xc7);
        q2.x = pk2(xa2 * xc8, xa2);
        q2.y = pk2(xa2 * xc0, xa2 * xc1);
        q2.z = pk2(xa2 * xc2, xa2 * xc3);
        q2.w = pk2(xa2 * xc4, xa2 * xc5);
        bf16x8 y0 = __builtin_bit_cast(bf16x8, q0);
        bf16x8 y1 = __builtin_bit_cast(bf16x8, q1);
        bf16x8 y2 = __builtin_bit_cast(bf16x8, q2);

        f32x4 acc0 = {0.f, 0.f, 0.f, 0.f}, acc1 = acc0, acc2 = acc0;
        acc0 = __builtin_amdgcn_mfma_f32_16x16x32_bf16(a00, y0, acc0, 0, 0, 0);
        acc0 = __builtin_amdgcn_mfma_f32_16x16x32_bf16(a01, y1, acc0, 0, 0, 0);
        acc0 = __builtin_amdgcn_mfma_f32_16x16x32_bf16(a02, y2, acc0, 0, 0, 0);
        acc1 = __builtin_amdgcn_mfma_f32_16x16x32_bf16(a10, y0, acc1, 0, 0, 0);
        acc1 = __builtin_amdgcn_mfma_f32_16x16x32_bf16(a11, y1, acc1, 0, 0, 0);
        acc1 = __builtin_amdgcn_mfma_f32_16x16x32_bf16(a12, y2, acc1, 0, 0, 0);
        acc2 = __builtin_amdgcn_mfma_f32_16x16x32_bf16(a20, y0, acc2, 0, 0, 0);
        acc2 = __builtin_amdgcn_mfma_f32_16x16x32_bf16(a21, y1, acc2, 0, 0, 0);
        acc2 = __builtin_amdgcn_mfma_f32_16x16x32_bf16(a22, y2, acc2, 0, 0, 0);

        f32x4 eA = (gg == 0) ? acc0 : (gg == 1) ? acc2 : (gg == 2) ? acc1 : acc0;
        f32x4 eB = (gg == 0) ? acc1 : (gg == 1) ? acc0 : (gg == 2) ? acc2 : acc1;
        f32x4 eC = (gg == 0) ? acc2 : (gg == 1) ? acc1 : (gg == 2) ? acc0 : acc2;
        float dA = eA[0] * xc0 + eA[1] * xc1 + eA[2] * xc2 + eA[3] * xc3;
        float dB = eB[0] * xc4 + eB[1] * xc5 + eB[2] * xc6 + eB[3] * xc7;
        float dC = eC[0] * xc8 + eC[1];
        float p0 = (gg == 0) ? dA : (gg == 1) ? dB : (gg == 2) ? dC : 0.f;
        float p1 = (gg == 0) ? dB : (gg == 1) ? dC : (gg == 2) ? 0.f : dA;
        float p2 = (gg == 0) ? dC : (gg == 1) ? 0.f : (gg == 2) ? dA : dB;
        float p3 = (gg == 0) ? 0.f : (gg == 1) ? dA : (gg == 2) ? dB : dC;
        p0 += __shfl_xor(p0, 16); p1 += __shfl_xor(p1, 16);
        p2 += __shfl_xor(p2, 16); p3 += __shfl_xor(p3, 16);
        p0 += __shfl_xor(p0, 32); p1 += __shfl_xor(p1, 32);
        p2 += __shfl_xor(p2, 32); p3 += __shfl_xor(p3, 32);
        float val = (gg == 0) ? p0 : (gg == 1) ? p1 : (gg == 2) ? p2 : p3;

        int pos = posw + sub * 64;
        if (gg == 3) f0t[(size_t)c * NPAD + pos] = val;
        else         f1t[(size_t)(c * 3 + gg) * NPAD + pos] = val;

        qa = qb; ha = hb; qb = qf; hb = hf;
    }
}

// ---------------- fused gate + equivariant linear (MFMA), 2-way split ----------
#define GSTR 264
__global__ __launch_bounds__(256) void k_post(
    const float* __restrict__ f0t, const float* __restrict__ f1t,
    const u16* __restrict__ gkf, const u16* __restrict__ linf,
    const float* __restrict__ gb, const int* __restrict__ order,
    const int* __restrict__ blk_sp, const int* __restrict__ vend,
    float* __restrict__ out) {
    int tile = blockIdx.x;
    int half = blockIdx.y;
    int s = blk_sp[tile >> 4];
    if (s < 0) return;
    int p0 = tile * 64;
    int vv = vend[tile >> 4];
    int boff = (tile & 15) * 64;

    __shared__ __align__(16) u16 frag[4][4][64][8];
    __shared__ __align__(16) u16 gate_l[64 * GSTR];
    __shared__ int ord[64];

    int t = threadIdx.x, lane = t & 63, w = t >> 6;
    int l15 = lane & 15, lg = lane >> 4;
    if (t < 64) ord[t] = (boff + t < vv) ? order[p0 + t] : -1;

#pragma unroll 1
    for (int it = 0; it < 32; ++it) {
        int posn = t & 63;
        int c = (t >> 6) + 4 * it;
        float v = f0t[(size_t)c * NPAD + p0 + posn];
        frag[posn >> 4][c >> 5][((c >> 3) & 3) * 16 + (posn & 15)][c & 7] = bf16rne(v);
    }
    __syncthreads();

#pragma unroll 1
    for (int kt = 0; kt < 16; ++kt) {
        float bias = gb[s * 256 + kt * 16 + l15];
        f32x4 acc = {bias, bias, bias, bias};
#pragma unroll
        for (int ck = 0; ck < 4; ++ck) {
            bf16x8 a = *(const bf16x8*)&frag[w][ck][lane][0];
            bf16x8 b = *(const bf16x8*)&gkf[(((size_t)(s * 16 + kt)) * 4 + ck) * 512 + lane * 8];
            acc = __builtin_amdgcn_mfma_f32_16x16x32_bf16(a, b, acc, 0, 0, 0);
        }
#pragma unroll
        for (int r = 0; r < 4; ++r) {
            int posn = w * 16 + lg * 4 + r;
            gate_l[posn * GSTR + kt * 16 + l15] = bf16rne(acc[r]);
        }
    }
    __syncthreads();

    const float INV = 0.08838834764831845f;   // 1/sqrt(128)

#pragma unroll 1
    for (int p = 2 * half; p < 2 * half + 2; ++p) {
#pragma unroll 1
        for (int it = 0; it < 4; ++it) {
            int rr = it * 256 + t;
            int pt = rr >> 8, ck = (rr >> 6) & 3, l2 = rr & 63;
            int posn = pt * 16 + (l2 & 15);
            int cb = ck * 32 + (l2 >> 4) * 8;
            u16 res[8];
            if (p == 0) {
                bf16x8 a1 = *(const bf16x8*)&frag[pt][ck][l2][0];
                const u16* gp = &gate_l[posn * GSTR + cb];
#pragma unroll
                for (int e = 0; e < 8; ++e)
                    res[e] = bf16rne(bf2f((u16)a1[e]) * bf2f(gp[e]));
            } else {
                int z = p - 1;
                const u16* gp = &gate_l[posn * GSTR + 128 + cb];
#pragma unroll
                for (int e = 0; e < 8; ++e) {
                    float fv = f1t[((size_t)(cb + e) * 3 + z) * NPAD + p0 + posn];
                    res[e] = bf16rne(fv * bf2f(gp[e]));
                }
            }
            uint4 uv;
            uv.x = (unsigned)res[0] | ((unsigned)res[1] << 16);
            uv.y = (unsigned)res[2] | ((unsigned)res[3] << 16);
            uv.z = (unsigned)res[4] | ((unsigned)res[5] << 16);
            uv.w = (unsigned)res[6] | ((unsigned)res[7] << 16);
            *(uint4*)&frag[pt][ck][l2][0] = uv;
        }
        __syncthreads();

        int lbase = (p == 0) ? 0 : 8;
#pragma unroll 1
        for (int kt = 0; kt < 8; ++kt) {
            f32x4 acc = {0.f, 0.f, 0.f, 0.f};
#pragma unroll
            for (int ck = 0; ck < 4; ++ck) {
                bf16x8 a = *(const bf16x8*)&frag[w][ck][lane][0];
                bf16x8 b = *(const bf16x8*)&linf[(((size_t)(lbase + kt)) * 4 + ck) * 512 + lane * 8];
                acc = __builtin_amdgcn_mfma_f32_16x16x32_bf16(a, b, acc, 0, 0, 0);
            }
            int k = kt * 16 + l15;
            int kk = (p == 0) ? k : (128 + k * 3 + (p - 1));
#pragma unroll
            for (int r = 0; r < 4; ++r) {
                int posn = w * 16 + lg * 4 + r;
                int n = ord[posn];
                if (n >= 0) out[(size_t)n * 512 + kk] = acc[r] * INV;
            }
        }
        __syncthreads();
    }
}

// ---------------------------------------------------------------------------
extern "C" void kernel_launch(void* const* d_in, const int* in_sizes, int n_in,
                              void* d_out, int out_size, void* d_ws, size_t ws_size,
                              hipStream_t stream) {
    const float* nf    = (const float*)d_in[0];
    const int*   sp    = (const int*)  d_in[1];
    const float* u1_0e = (const float*)d_in[2];
    const float* u2_0e = (const float*)d_in[3];
    const float* u3_0e = (const float*)d_in[4];
    const float* u1_1o = (const float*)d_in[5];
    const float* u2_1o = (const float*)d_in[6];
    const float* u3_1o = (const float*)d_in[7];
    const float* w1_0e = (const float*)d_in[8];
    const float* w2_0e = (const float*)d_in[9];
    const float* w3_0e = (const float*)d_in[10];
    const float* w1_1o = (const float*)d_in[11];
    const float* w2_1o = (const float*)d_in[12];
    const float* w3_1o = (const float*)d_in[13];
    const float* gk    = (const float*)d_in[14];
    const float* gb    = (const float*)d_in[15];
    const float* lin0  = (const float*)d_in[16];
    const float* lin1  = (const float*)d_in[17];

    float* ws   = (float*)d_ws;
    u16*  af    = (u16*)(ws + OFF_AF);
    float* f0t  = ws + OFF_F0;
    float* f1t  = ws + OFF_F1;
    u16*  gkf   = (u16*)(ws + OFF_GKF);
    u16*  linf  = (u16*)(ws + OFF_LINF);
    int* order  = (int*)(ws + OFF_ORD);
    int* meta   = (int*)(ws + OFF_META);
    u16*  xt8   = (u16*)(ws + OFF_XT8);
    uint* xt1   = (uint*)(ws + OFF_XT1);
    int* cursor = meta + 16;
    int* blk_sp = meta + 32;
    int* vend   = meta + 64;

    k_plan<<<1, 256, 0, stream>>>(sp, cursor, blk_sp, vend);
    k_setup2<<<SC_BLK + P2_BLK + 88, 512, 0, stream>>>(
        sp, cursor, order,
        u1_0e, u2_0e, u3_0e, u1_1o, u2_1o, u3_1o,
        w1_0e, w2_0e, w3_0e, w1_1o, w2_1o, w3_1o, af,
        gk, lin0, lin1, gkf, linf);
    k_xpose<<<NPAD / 16, 256, 0, stream>>>(nf, order, blk_sp, vend, xt8, xt1);
    k_contract<<<5120, 128, 0, stream>>>(xt8, xt1, blk_sp, af, f0t, f1t);
    dim3 gpost(NPAD / 64, 2);
    k_post<<<gpost, 256, 0, stream>>>(f0t, f1t, gkf, linf, gb, order, blk_sp, vend,
                                      (float*)d_out);
}